// Round 2
// baseline (214.914 us; speedup 1.0000x reference)
//
#include <hip/hip_runtime.h>
#include <math.h>

// DistanceNetwork: out[b,i] = (query[b] . support[b,i]) * rsqrt(max(|support[b,i]|^2, EPS))
// support: [B=2048, CK=256, D=512] fp32, query: [B, D] fp32, out: [B, CK] fp32.
// Memory-bound: stream 1 GiB of support once. Roofline ~171 us @ 6.3 TB/s.
//
// Layout: 1 block (4 waves) per batch b. Each wave owns 64 rows, processed
// 4 rows per iteration by 4x 16-lane groups. Lane j of group g loads 8
// contiguous float4s of its row (128 B/lane, 8 KB in flight per wave), then a
// 4-step __shfl_xor butterfly within the 16-lane group reduces (dot, nrm) --
// 2 shuffles/row vs 12 in the 64-lane-per-row variant.

#define B_DIM  2048
#define CK_DIM 256
#define D_DIM  512
#define EPS_F  1e-10f

__global__ __launch_bounds__(256) void distance_net_kernel(
    const float* __restrict__ support,
    const float* __restrict__ query,
    float* __restrict__ out)
{
    const int b    = blockIdx.x;
    const int tid  = threadIdx.x;
    const int lane = tid & 63;
    const int wave = tid >> 6;   // 4 waves per block
    const int j    = lane & 15;  // position within 16-lane group
    const int g    = lane >> 4;  // group 0..3

    // Query fragment for this lane: float4 indices j, j+16, ..., j+112.
    const float4* q4 = reinterpret_cast<const float4*>(query + (size_t)b * D_DIM);
    float4 qf[8];
    #pragma unroll
    for (int k = 0; k < 8; ++k) qf[k] = q4[j + 16 * k];

    const float* sup_b = support + (size_t)b * CK_DIM * D_DIM;
    float* out_b = out + (size_t)b * CK_DIM;

    // Wave handles rows [wave*64, wave*64+64), 4 consecutive rows per iteration.
    #pragma unroll 2
    for (int it = 0; it < 16; ++it) {
        const int row = wave * 64 + it * 4 + g;
        const float4* s4 = reinterpret_cast<const float4*>(sup_b + (size_t)row * D_DIM);

        float4 sf[8];
        #pragma unroll
        for (int k = 0; k < 8; ++k) sf[k] = s4[j + 16 * k];

        float dot = 0.f, nrm = 0.f;
        #pragma unroll
        for (int k = 0; k < 8; ++k) {
            dot += sf[k].x * qf[k].x + sf[k].y * qf[k].y
                 + sf[k].z * qf[k].z + sf[k].w * qf[k].w;
            nrm += sf[k].x * sf[k].x + sf[k].y * sf[k].y
                 + sf[k].z * sf[k].z + sf[k].w * sf[k].w;
        }

        // 16-lane butterfly (off < 16 stays within the group).
        #pragma unroll
        for (int off = 8; off >= 1; off >>= 1) {
            dot += __shfl_xor(dot, off);
            nrm += __shfl_xor(nrm, off);
        }

        if (j == 0) {
            out_b[row] = dot * rsqrtf(fmaxf(nrm, EPS_F));
        }
    }
}

extern "C" void kernel_launch(void* const* d_in, const int* in_sizes, int n_in,
                              void* d_out, int out_size, void* d_ws, size_t ws_size,
                              hipStream_t stream) {
    const float* support = (const float*)d_in[0];
    const float* query   = (const float*)d_in[1];
    float* out           = (float*)d_out;

    dim3 grid(B_DIM);
    dim3 block(256);
    distance_net_kernel<<<grid, block, 0, stream>>>(support, query, out);
}

// Round 4
// 169.302 us; speedup vs baseline: 1.2694x; 1.2694x over previous
//
#include <hip/hip_runtime.h>
#include <math.h>

// DistanceNetwork: out[b,i] = (query[b] . support[b,i]) * rsqrt(max(|support[b,i]|^2, EPS))
// support: [B=2048, CK=256, D=512] fp32, query: [B, D] fp32, out: [B, CK] fp32.
// Memory-bound: stream 1 GiB of support once. Roofline ~171 us @ 6.3 TB/s.
//
// R1 structure (best so far, 199 us): 1 block (4 waves) per batch, 64 lanes
// per row, 2x float4 loads per lane, 6-step butterfly. This round adds:
//  - explicit 1-row software pipeline: next row's loads issue BEFORE the
//    current row's butterfly, so the load pipe never idles behind the
//    12-op dependent shuffle chain;
//  - nontemporal loads on the support stream (read-once, evict-first).
// Uses a clang ext_vector float4 (fx4) because __builtin_nontemporal_load
// rejects HIP_vector_type.

#define B_DIM  2048
#define CK_DIM 256
#define D_DIM  512
#define EPS_F  1e-10f

typedef float fx4 __attribute__((ext_vector_type(4)));

__global__ __launch_bounds__(256) void distance_net_kernel(
    const float* __restrict__ support,
    const float* __restrict__ query,
    float* __restrict__ out)
{
    const int b    = blockIdx.x;
    const int tid  = threadIdx.x;
    const int lane = tid & 63;
    const int wave = tid >> 6;   // 4 waves per block

    // Query fragment in registers: elements [4l..4l+3] and [256+4l..256+4l+3].
    const fx4* q4 = reinterpret_cast<const fx4*>(query + (size_t)b * D_DIM);
    const fx4 qa = q4[lane];
    const fx4 qb = q4[64 + lane];

    const fx4* s4 = reinterpret_cast<const fx4*>(support + (size_t)b * CK_DIM * D_DIM);
    float* out_b = out + (size_t)b * CK_DIM;

    // Wave handles rows wave, wave+4, ..., wave+252 (64 rows). Row r spans
    // float4 indices [r*128, r*128+128): two coalesced 1 KiB segments.
    int row = wave;
    fx4 sa = __builtin_nontemporal_load(s4 + (size_t)row * 128 + lane);
    fx4 sb = __builtin_nontemporal_load(s4 + (size_t)row * 128 + 64 + lane);

    for (int it = 0; it < 64; ++it) {
        // Prefetch next row BEFORE the dependent reduction chain.
        const int prow = (it < 63) ? row + 4 : row;  // clamp: no OOB on last iter
        const fx4 na = __builtin_nontemporal_load(s4 + (size_t)prow * 128 + lane);
        const fx4 nb = __builtin_nontemporal_load(s4 + (size_t)prow * 128 + 64 + lane);

        float dot = sa.x * qa.x + sa.y * qa.y + sa.z * qa.z + sa.w * qa.w
                  + sb.x * qb.x + sb.y * qb.y + sb.z * qb.z + sb.w * qb.w;
        float nrm = sa.x * sa.x + sa.y * sa.y + sa.z * sa.z + sa.w * sa.w
                  + sb.x * sb.x + sb.y * sb.y + sb.z * sb.z + sb.w * sb.w;

        // 64-lane butterfly reduction of (dot, nrm).
        #pragma unroll
        for (int off = 32; off >= 1; off >>= 1) {
            dot += __shfl_xor(dot, off);
            nrm += __shfl_xor(nrm, off);
        }

        if (lane == 0) {
            out_b[row] = dot * rsqrtf(fmaxf(nrm, EPS_F));
        }

        sa = na;
        sb = nb;
        row = prow;
    }
}

extern "C" void kernel_launch(void* const* d_in, const int* in_sizes, int n_in,
                              void* d_out, int out_size, void* d_ws, size_t ws_size,
                              hipStream_t stream) {
    const float* support = (const float*)d_in[0];
    const float* query   = (const float*)d_in[1];
    float* out           = (float*)d_out;

    dim3 grid(B_DIM);
    dim3 block(256);
    distance_net_kernel<<<grid, block, 0, stream>>>(support, query, out);
}